// Round 1
// baseline (836.082 us; speedup 1.0000x reference)
//
#include <hip/hip_runtime.h>

// LIF constants (fp32 renderings of the reference's Python floats)
// tau_m = R*C = 150.00000000000003 -> fp32(tm) = 150.0f exactly.
#define DT_F    0.01f
#define TM_F    150.0f
#define R_F     3000.0f
#define V_THR_F 15.0f
#define V_MAX_F 30.0f

// ROUND 4: rolling register prefetch (depth PF), replacing the round-1
// burst-of-8 structure.
//
// Why: round-1 measured 818 us vs a 167 us streaming roofline (1.05 GB at
// 6.3 TB/s). Little's law on the read side (1.04 B/cyc/CU achieved) says
// average outstanding loads/wave was ~1, not 8: the U=8 block issued its
// loads only after the previous block's compute AND stores, so the wave
// drained to zero outstanding every 8 steps and its progress was chained
// to its own store retirement (vmcnt retires in issue order).
//
// Fix: every step consumes s[u] and immediately reissues that slot's load
// PF steps ahead, BEFORE the current step's store. Steady state keeps
// ~PF loads/wave in flight (8 waves/CU x PF x 256 B = 40 KB/CU) and gives
// each store PF steps of slack before any wait can be chained to it.
// Outstanding vm ops at any wait point: ~(PF-1) loads + PF stores = 39 < 63
// (vmcnt field limit) for PF=20.
//
// NUMERICS UNCHANGED from the passing round-1 kernel: identical expression,
// identical op order, fp contraction off. A single FMA or a reciprocal-mul
// can flip a spike at the v>=15 threshold and blow absmax to 30.
template <int PF>
__global__ __launch_bounds__(256) void lif_kernel(const float* __restrict__ stim,
                                                  float* __restrict__ out,
                                                  int T, int N) {
#pragma clang fp contract(off)
    static_assert(1000 % PF == 0, "PF must divide T");
    const int n = blockIdx.x * blockDim.x + threadIdx.x;
    if (n >= N) return;

    // 32-bit element indices: max index = 131,071,999 < 2^31 and byte
    // offset < 2^31, so the compiler can use sgpr-base + 32b-voffset
    // addressing with a single v_add per step instead of 64-bit pointer math.
    const unsigned stride = (unsigned)N;
    unsigned ld = (unsigned)n;   // element index of the next load
    unsigned st = (unsigned)n;   // element index of the next store

    // Prologue: fill the pipeline with PF loads (steps 0..PF-1).
    float s[PF];
#pragma unroll
    for (int u = 0; u < PF; ++u) { s[u] = stim[ld]; ld += stride; }

    float v = 0.0f;
    const int rounds = T / PF - 1;   // main rounds; last PF steps have no refill
    for (int r = 0; r < rounds; ++r) {
#pragma unroll
        for (int u = 0; u < PF; ++u) {
            float cur = s[u];
            // Refill this slot PF steps ahead. Issued before the compute's
            // waitcnt on `cur` and before this step's store, so the load
            // queue never drains and no wait is chained to young stores.
            s[u] = stim[ld]; ld += stride;

            // step 1: reset-from-spike OR Euler step (exact ref op order)
            float v_euler = v + ((-v + R_F * cur) / TM_F) * DT_F;
            float vn = (v >= V_THR_F) ? 0.0f : v_euler;
            // step 2: spike clamp
            vn = (vn >= V_THR_F) ? V_MAX_F : vn;
            v = vn;

            // Streaming output, never re-read: nontemporal keeps L2 from
            // write-allocating against the stim read stream.
            __builtin_nontemporal_store(v, &out[st]);
            st += stride;
        }
    }

    // Epilogue: consume the last PF slots, no refill.
#pragma unroll
    for (int u = 0; u < PF; ++u) {
        float cur = s[u];
        float v_euler = v + ((-v + R_F * cur) / TM_F) * DT_F;
        float vn = (v >= V_THR_F) ? 0.0f : v_euler;
        vn = (vn >= V_THR_F) ? V_MAX_F : vn;
        v = vn;
        __builtin_nontemporal_store(v, &out[st]);
        st += stride;
    }
}

extern "C" void kernel_launch(void* const* d_in, const int* in_sizes, int n_in,
                              void* d_out, int out_size, void* d_ws, size_t ws_size,
                              hipStream_t stream) {
    const float* stim = (const float*)d_in[0];
    float*       out  = (float*)d_out;

    constexpr int T = 1000;
    constexpr int N = 131072;   // in_sizes[0] == T*N == 131072000

    constexpr int BLOCK = 256;
    const int grid = (N + BLOCK - 1) / BLOCK;   // 512 blocks -> 2 blocks/CU, 8 waves/CU
    lif_kernel<20><<<grid, BLOCK, 0, stream>>>(stim, out, T, N);
}